// Round 2
// baseline (611.222 us; speedup 1.0000x reference)
//
#include <hip/hip_runtime.h>
#include <hip/hip_bf16.h>
#include <math.h>

typedef __hip_bfloat16 bf16;
typedef __attribute__((ext_vector_type(8))) short bf16x8;   // 8 x bf16 = 4 VGPRs
typedef __attribute__((ext_vector_type(4))) float f32x4;

#define D_MODEL 1024
#define N_HEADS 16
#define HEAD_D  64
#define SEQ     2048
#define BATCH   4
#define NROWS   (BATCH*SEQ)   // 8192

#define MFMA(a,b,c) __builtin_amdgcn_mfma_f32_16x16x32_bf16(a,b,c,0,0,0)

// async global->LDS, 16B per lane. LDS dest = wave-uniform base + lane*16.
__device__ __forceinline__ void gload16(void* lds_uniform_base, const void* g) {
  __builtin_amdgcn_global_load_lds(
      (const __attribute__((address_space(1))) void*)g,
      (__attribute__((address_space(3))) void*)lds_uniform_base,
      16, 0, 0);
}

__device__ __forceinline__ short f2bs(float x) {
  return (short)__bfloat16_as_ushort(__float2bfloat16(x));
}

__device__ __forceinline__ bf16x8 cvt8(float4 a, float4 b) {
  union { bf16x8 v; short s[8]; } u;
  u.s[0] = f2bs(a.x); u.s[1] = f2bs(a.y); u.s[2] = f2bs(a.z); u.s[3] = f2bs(a.w);
  u.s[4] = f2bs(b.x); u.s[5] = f2bs(b.y); u.s[6] = f2bs(b.z); u.s[7] = f2bs(b.w);
  return u.v;
}

// -------------------------------------------------------------------------
// C(Mx1024) = X(Mx1024) @ W(1024x1024)^T + bias.
// X dtype: A_F32 ? float : bf16.  W dtype: B_F32 ? float : bf16.
// MODE 0: out float row-major (final O-projection)
// MODE 1: out bf16 [((b*16+h)*2048 + m)*64 + d]        (K layout)
// MODE 2: out bf16 [((b*16+h)*64 + d)*2048 + m]        (V^T layout)
// MODE 3: RoPE, out bf16 [((b*16+h)*2048 + t)*64 + d]  (Q layout)
// block 256 (4 waves), tile 128x128, BK=64, K=1024 fixed.
// LDS layout: 128 rows x 128B; 16B chunk c of row r stored at chunk c^(r&7).
// -------------------------------------------------------------------------
template<int MODE, bool A_F32, bool B_F32>
__global__ __launch_bounds__(256, 2)
void gemm_bt(const void* __restrict__ Xv, const void* __restrict__ Wv,
             const float* __restrict__ bias, void* __restrict__ outv,
             const int* __restrict__ pos) {
  __shared__ bf16 sA[128*64];
  __shared__ bf16 sB[128*64];

  const float* Xf = (const float*)Xv;
  const bf16*  Xb = (const bf16*) Xv;
  const float* Wf = (const float*)Wv;
  const bf16*  Wb = (const bf16*) Wv;

  const int tid  = threadIdx.x;
  const int lane = tid & 63, wid = tid >> 6;
  const int q4 = lane >> 4, l15 = lane & 15;
  const int rb = blockIdx.x * 128;
  const int cb = blockIdx.y * 128;
  const int wm = (wid >> 1) * 64, wn = (wid & 1) * 64;

  f32x4 acc[4][4];
  const f32x4 z4 = {0.f, 0.f, 0.f, 0.f};
#pragma unroll
  for (int i = 0; i < 4; ++i)
#pragma unroll
    for (int j = 0; j < 4; ++j) acc[i][j] = z4;

  for (int kt = 0; kt < 16; ++kt) {
    const int k0 = kt * 64;
    // stage A,B: per issue 256 thr x 8 elems; 4 issues cover 128x64
#pragma unroll
    for (int i = 0; i < 4; ++i) {
      int e  = i*2048 + tid*8;       // element index within 128x64 tile
      int rr = e >> 6;               // tile row
      int c  = (e >> 3) & 7;         // 8-elem chunk within row
      int cs = c ^ (rr & 7);         // swizzled LDS chunk
      bf16x8 va, vb;
      if (A_F32) {
        const float* s0 = Xf + (size_t)(rb + rr)*D_MODEL + k0 + c*8;
        va = cvt8(*(const float4*)s0, *(const float4*)(s0 + 4));
      } else {
        va = *(const bf16x8*)(Xb + (size_t)(rb + rr)*D_MODEL + k0 + c*8);
      }
      if (B_F32) {
        const float* s1 = Wf + (size_t)(cb + rr)*D_MODEL + k0 + c*8;
        vb = cvt8(*(const float4*)s1, *(const float4*)(s1 + 4));
      } else {
        vb = *(const bf16x8*)(Wb + (size_t)(cb + rr)*D_MODEL + k0 + c*8);
      }
      *(bf16x8*)((char*)sA + rr*128 + cs*16) = va;
      *(bf16x8*)((char*)sB + rr*128 + cs*16) = vb;
    }
    __syncthreads();
#pragma unroll
    for (int kq = 0; kq < 2; ++kq) {
      bf16x8 af[4], bfr[4];
      const int cc = (kq*4 + q4) ^ (l15 & 7);
#pragma unroll
      for (int mi = 0; mi < 4; ++mi) {
        int r = wm + mi*16 + l15;
        af[mi] = *(const bf16x8*)((const char*)sA + r*128 + cc*16);
      }
#pragma unroll
      for (int ni = 0; ni < 4; ++ni) {
        int r = wn + ni*16 + l15;
        bfr[ni] = *(const bf16x8*)((const char*)sB + r*128 + cc*16);
      }
#pragma unroll
      for (int mi = 0; mi < 4; ++mi)
#pragma unroll
        for (int ni = 0; ni < 4; ++ni)
          acc[mi][ni] = MFMA(af[mi], bfr[ni], acc[mi][ni]);
    }
    __syncthreads();
  }

  // ---------------- epilogue ----------------
  if (MODE == 0) {
    float* outF = (float*)outv;
#pragma unroll
    for (int ni = 0; ni < 4; ++ni) {
      int col = cb + wn + ni*16 + l15;
      float bv = bias[col];
#pragma unroll
      for (int mi = 0; mi < 4; ++mi) {
        int row0 = rb + wm + mi*16 + q4*4;
#pragma unroll
        for (int r = 0; r < 4; ++r)
          outF[(size_t)(row0 + r)*D_MODEL + col] = acc[mi][ni][r] + bv;
      }
    }
  } else if (MODE == 1 || MODE == 2) {
    bf16* out = (bf16*)outv;
#pragma unroll
    for (int ni = 0; ni < 4; ++ni) {
      int col = cb + wn + ni*16 + l15;
      int h = col >> 6, d = col & 63;
      float bv = bias[col];
#pragma unroll
      for (int mi = 0; mi < 4; ++mi) {
#pragma unroll
        for (int r = 0; r < 4; ++r) {
          int row = rb + wm + mi*16 + q4*4 + r;
          int b = row >> 11, m = row & 2047;
          size_t idx = (MODE == 1)
              ? ((size_t)((b*N_HEADS + h)*SEQ + m)*HEAD_D + d)
              : ((size_t)((b*N_HEADS + h)*HEAD_D + d)*SEQ + m);
          out[idx] = __float2bfloat16(acc[mi][ni][r] + bv);
        }
      }
    }
  } else { // MODE 3: Q with RoPE
    bf16* out = (bf16*)outv;
    // robust to int32 or int64 storage of position ids: positions are sorted
    // ascending per batch ending ~4090, so int32 slot 8191 is only 0 when the
    // buffer is int64 (hi half of element 4095).
    const bool is64 = (pos[NROWS - 1] == 0);
    const float CLOG = 13.287712379549449f / 32.0f;  // log2(10000)/32
    float invf0 = exp2f(-(float)(l15)      * CLOG);
    float invf1 = exp2f(-(float)(l15 + 16) * CLOG);
    int h = (cb + wn) >> 6;  // wave covers exactly one head (64 cols)
#pragma unroll
    for (int ni = 0; ni < 2; ++ni) {
      int col1 = cb + wn + ni*16 + l15;
      int d = ni*16 + l15;          // d in [0,32)
      float invf = (ni == 0) ? invf0 : invf1;
      float b1 = bias[col1];
      float b2 = bias[col1 + 32];
#pragma unroll
      for (int mi = 0; mi < 4; ++mi) {
#pragma unroll
        for (int r = 0; r < 4; ++r) {
          int row = rb + wm + mi*16 + q4*4 + r;
          int b = row >> 11, t = row & 2047;
          int pv = is64 ? pos[2*row] : pos[row];
          float ang = (float)pv * invf;
          float sn, cs;
          __sincosf(ang, &sn, &cs);
          float q1 = acc[mi][ni][r]   + b1;
          float q2 = acc[mi][ni+2][r] + b2;
          size_t base = (size_t)((b*N_HEADS + h)*SEQ + t)*HEAD_D;
          out[base + d]      = __float2bfloat16(q1*cs - q2*sn);
          out[base + d + 32] = __float2bfloat16(q2*cs + q1*sn);
        }
      }
    }
  }
}

// -------------------------------------------------------------------------
// Flash attention. grid = (T/128, B*H). block = 256 (4 waves x 32 q-rows).
// Q[bh][t][d], K[bh][m][d], VT[bh][d][m] all bf16. O -> [b][t][h*64+d].
// -------------------------------------------------------------------------
__global__ __launch_bounds__(256, 2)
void attn_kernel(const bf16* __restrict__ Q, const bf16* __restrict__ K,
                 const bf16* __restrict__ VT, bf16* __restrict__ O) {
  // sP (128x136 bf16 = 34816B) aliases sK (128x64 = 16KB); sVT separate.
  __shared__ __align__(16) char smem[34816 + 16384];
  bf16* sP  = (bf16*)smem;
  bf16* sK  = (bf16*)smem;
  bf16* sVT = (bf16*)(smem + 34816);

  const int tid  = threadIdx.x;
  const int lane = tid & 63, wid = tid >> 6;
  const int q4 = lane >> 4, l15 = lane & 15;
  const int bh = blockIdx.y;
  const int qb = blockIdx.x * 128;

  const bf16* Qp  = Q  + (size_t)bh * SEQ * HEAD_D;
  const bf16* Kp  = K  + (size_t)bh * SEQ * HEAD_D;
  const bf16* VTp = VT + (size_t)bh * HEAD_D * SEQ;

  // resident Q fragments: wave owns rows [qb+wid*32, +32)
  bf16x8 qf[2][2];
#pragma unroll
  for (int mi = 0; mi < 2; ++mi)
#pragma unroll
    for (int kq = 0; kq < 2; ++kq) {
      int t = qb + wid*32 + mi*16 + l15;
      qf[mi][kq] = *(const bf16x8*)(Qp + (size_t)t*HEAD_D + kq*32 + q4*8);
    }

  const f32x4 z4 = {0.f, 0.f, 0.f, 0.f};
  f32x4 oacc[2][4];
  float mrow[2][4], lrow[2][4];
#pragma unroll
  for (int mi = 0; mi < 2; ++mi) {
#pragma unroll
    for (int nd = 0; nd < 4; ++nd) oacc[mi][nd] = z4;
#pragma unroll
    for (int r = 0; r < 4; ++r) { mrow[mi][r] = -3.0e38f; lrow[mi][r] = 0.f; }
  }

  for (int kv = 0; kv < 16; ++kv) {
    const int m0 = kv * 128;
    // stage K tile (128x64, swizzled 16B chunks within 128B rows)
#pragma unroll
    for (int i = 0; i < 4; ++i) {
      int o  = i*4096 + tid*16;
      int rr = o >> 7;
      int c0 = ((o >> 4) & 7) ^ (rr & 7);
      gload16((char*)sK + i*4096 + (wid << 10),
              Kp + (size_t)(m0 + rr)*HEAD_D + c0*8);
    }
    // stage VT tile (64x128, swizzled 16B chunks within 256B rows)
#pragma unroll
    for (int i = 0; i < 4; ++i) {
      int o  = i*4096 + tid*16;
      int rr = o >> 8;
      int c0 = ((o >> 4) & 15) ^ (rr & 7);
      gload16((char*)sVT + i*4096 + (wid << 10),
              VTp + (size_t)rr*SEQ + m0 + c0*8);
    }
    __syncthreads();

    // S = (Q K^T) * 0.125
    f32x4 s[2][8];
#pragma unroll
    for (int mi = 0; mi < 2; ++mi)
#pragma unroll
      for (int ni = 0; ni < 8; ++ni) s[mi][ni] = z4;
#pragma unroll
    for (int kq = 0; kq < 2; ++kq) {
      const int cc = (kq*4 + q4) ^ (l15 & 7);
#pragma unroll
      for (int ni = 0; ni < 8; ++ni) {
        int m = ni*16 + l15;
        bf16x8 bk = *(const bf16x8*)((const char*)sK + m*128 + cc*16);
        s[0][ni] = MFMA(qf[0][kq], bk, s[0][ni]);
        s[1][ni] = MFMA(qf[1][kq], bk, s[1][ni]);
      }
    }
    __syncthreads();   // all sK reads done before sP (aliased) is written
#pragma unroll
    for (int mi = 0; mi < 2; ++mi)
#pragma unroll
      for (int ni = 0; ni < 8; ++ni) s[mi][ni] *= 0.125f;

    // online softmax (rows r = q4*4+0..3 per 16x16 tile), then P -> LDS
#pragma unroll
    for (int mi = 0; mi < 2; ++mi) {
      float mloc[4] = {-3.0e38f, -3.0e38f, -3.0e38f, -3.0e38f};
#pragma unroll
      for (int ni = 0; ni < 8; ++ni)
#pragma unroll
        for (int r = 0; r < 4; ++r) mloc[r] = fmaxf(mloc[r], s[mi][ni][r]);
#pragma unroll
      for (int off = 1; off < 16; off <<= 1)
#pragma unroll
        for (int r = 0; r < 4; ++r)
          mloc[r] = fmaxf(mloc[r], __shfl_xor(mloc[r], off, 64));
      float al[4], rs[4] = {0.f, 0.f, 0.f, 0.f};
#pragma unroll
      for (int r = 0; r < 4; ++r) {
        float mn = fmaxf(mrow[mi][r], mloc[r]);
        al[r] = __expf(mrow[mi][r] - mn);
        mrow[mi][r] = mn;
      }
#pragma unroll
      for (int ni = 0; ni < 8; ++ni)
#pragma unroll
        for (int r = 0; r < 4; ++r) {
          float p = __expf(s[mi][ni][r] - mrow[mi][r]);
          s[mi][ni][r] = p;
          rs[r] += p;
        }
#pragma unroll
      for (int off = 1; off < 16; off <<= 1)
#pragma unroll
        for (int r = 0; r < 4; ++r) rs[r] += __shfl_xor(rs[r], off, 64);
#pragma unroll
      for (int r = 0; r < 4; ++r) lrow[mi][r] = lrow[mi][r]*al[r] + rs[r];
#pragma unroll
      for (int nd = 0; nd < 4; ++nd)
#pragma unroll
        for (int r = 0; r < 4; ++r) oacc[mi][nd][r] *= al[r];
      // P: C-layout scatter into padded LDS (ld = 136 elems)
#pragma unroll
      for (int ni = 0; ni < 8; ++ni)
#pragma unroll
        for (int r = 0; r < 4; ++r)
          sP[(wid*32 + mi*16 + q4*4 + r)*136 + ni*16 + l15] =
              __float2bfloat16(s[mi][ni][r]);
    }
    __syncthreads();

    // O += P @ V   (A from sP rows, B from sVT rows = V^T)
#pragma unroll
    for (int kk = 0; kk < 4; ++kk) {
      bf16x8 bv[4];
      const int cc = (kk*4 + q4) ^ (l15 & 7);
#pragma unroll
      for (int nd = 0; nd < 4; ++nd) {
        int d = nd*16 + l15;
        bv[nd] = *(const bf16x8*)((const char*)sVT + d*256 + cc*16);
      }
#pragma unroll
      for (int mi = 0; mi < 2; ++mi) {
        bf16x8 ap = *(const bf16x8*)((const char*)sP +
                     (wid*32 + mi*16 + l15)*272 + kk*64 + q4*16);
#pragma unroll
        for (int nd = 0; nd < 4; ++nd)
          oacc[mi][nd] = MFMA(ap, bv[nd], oacc[mi][nd]);
      }
    }
    __syncthreads();   // PV reads done before next tile overwrites sK/sVT
  }

  // epilogue: O /= l, write [b][t][h*64+d]
  const int b = bh >> 4, h = bh & 15;
#pragma unroll
  for (int mi = 0; mi < 2; ++mi) {
#pragma unroll
    for (int r = 0; r < 4; ++r) {
      int t = qb + wid*32 + mi*16 + q4*4 + r;
      float inv = 1.0f / lrow[mi][r];
#pragma unroll
      for (int nd = 0; nd < 4; ++nd) {
        int d = nd*16 + l15;
        O[(size_t)(b*SEQ + t)*D_MODEL + h*HEAD_D + d] =
            __float2bfloat16(oacc[mi][nd][r] * inv);
      }
    }
  }
}

// -------------------------------------------------------------------------
extern "C" void kernel_launch(void* const* d_in, const int* in_sizes, int n_in,
                              void* d_out, int out_size, void* d_ws, size_t ws_size,
                              hipStream_t stream) {
  const void*  query = d_in[0];            // f32 [B,T,D]
  const void*  key   = d_in[1];            // f32 [B,M,D]
  const void*  value = d_in[2];            // f32 [B,M,D]
  const int*   pos   = (const int*)d_in[3];
  const void*  Wq = d_in[4];  const float* bq = (const float*)d_in[5];
  const void*  Wk = d_in[6];  const float* bk = (const float*)d_in[7];
  const void*  Wv = d_in[8];  const float* bv = (const float*)d_in[9];
  const void*  Wo = d_in[10]; const float* bo = (const float*)d_in[11];

  // workspace: 4 x 16MB bf16 buffers (needs 64MB)
  char* ws = (char*)d_ws;
  bf16* qbuf  = (bf16*)(ws);                       // [b,h,t,d]
  bf16* kbuf  = (bf16*)(ws + (size_t)16777216);    // [b,h,m,d]
  bf16* vtbuf = (bf16*)(ws + (size_t)33554432);    // [b,h,d,m]
  bf16* obuf  = (bf16*)(ws + (size_t)50331648);    // [b,t,h*64+d]

  dim3 blk(256);
  dim3 gproj(NROWS/128, D_MODEL/128);   // 64 x 8

  gemm_bt<3, true, true ><<<gproj, blk, 0, stream>>>(query, Wq, bq, qbuf, pos);
  gemm_bt<1, true, true ><<<gproj, blk, 0, stream>>>(key,   Wk, bk, kbuf, nullptr);
  gemm_bt<2, true, true ><<<gproj, blk, 0, stream>>>(value, Wv, bv, vtbuf, nullptr);
  attn_kernel<<<dim3(SEQ/128, BATCH*N_HEADS), blk, 0, stream>>>(qbuf, kbuf, vtbuf, obuf);
  gemm_bt<0, false, true><<<gproj, blk, 0, stream>>>(obuf, Wo, bo, d_out, nullptr);
  (void)in_sizes; (void)n_in; (void)out_size; (void)ws_size;
}

// Round 3
// 442.892 us; speedup vs baseline: 1.3801x; 1.3801x over previous
//
#include <hip/hip_runtime.h>
#include <hip/hip_bf16.h>
#include <math.h>

typedef __hip_bfloat16 bf16;
typedef __attribute__((ext_vector_type(8))) short bf16x8;   // 8 x bf16 = 4 VGPRs
typedef __attribute__((ext_vector_type(4))) float f32x4;

#define D_MODEL 1024
#define N_HEADS 16
#define HEAD_D  64
#define SEQ     2048
#define BATCH   4
#define NROWS   (BATCH*SEQ)   // 8192

// softmax scale folded into Q at projection time: 1/sqrt(64) * log2(e)
#define SCALE_Q 0.18033688011112042f

#define MFMA(a,b,c) __builtin_amdgcn_mfma_f32_16x16x32_bf16(a,b,c,0,0,0)

#if __has_builtin(__builtin_amdgcn_exp2f)
#define EXP2(x) __builtin_amdgcn_exp2f(x)
#else
#define EXP2(x) exp2f(x)
#endif

// async global->LDS, 16B per lane. LDS dest = wave-uniform base + lane*16.
__device__ __forceinline__ void gload16(void* lds_uniform_base, const void* g) {
  __builtin_amdgcn_global_load_lds(
      (const __attribute__((address_space(1))) void*)g,
      (__attribute__((address_space(3))) void*)lds_uniform_base,
      16, 0, 0);
}

// fast packed f32->bf16 RNE: lo = a, hi = b
__device__ __forceinline__ unsigned pkrne(float a, float b) {
  unsigned ua = __float_as_uint(a), ub = __float_as_uint(b);
  ua += 0x7FFFu + ((ua >> 16) & 1u);
  ub += 0x7FFFu + ((ub >> 16) & 1u);
  return (ua >> 16) | (ub & 0xFFFF0000u);
}
__device__ __forceinline__ bf16x8 cvt8rne(float4 a, float4 b) {
  union { bf16x8 v; unsigned u[4]; } u;
  u.u[0] = pkrne(a.x, a.y); u.u[1] = pkrne(a.z, a.w);
  u.u[2] = pkrne(b.x, b.y); u.u[3] = pkrne(b.z, b.w);
  return u.v;
}

// f32 -> bf16 bulk convert (weights). grid*256*8 == count.
__global__ __launch_bounds__(256)
void convw(const float* __restrict__ src, bf16* __restrict__ dst) {
  int idx = (blockIdx.x * 256 + threadIdx.x) * 8;
  float4 a = *(const float4*)(src + idx);
  float4 b = *(const float4*)(src + idx + 4);
  *(bf16x8*)(dst + idx) = cvt8rne(a, b);
}

// -------------------------------------------------------------------------
// C(M'x N') = A(M'x1024) @ B(N'x1024)^T + bias, K=1024.
// A dtype: A_BF16 ? bf16 (global_load_lds) : f32 (register cvt).  Same for B.
// MODE 0: out f32 row-major, bias[col]        (O-projection)
// MODE 1: out bf16 K-layout  [((b*16+h)*2048+m)*64+d], bias[col]
// MODE 2: flipped V: row=h*64+d, col=b*2048+m; out[(b*1024+row)*2048+m],
//         bias[row]
// MODE 3: RoPE Q scaled by SCALE_Q, out bf16 [((b*16+h)*2048+t)*64+d]
// block 256 (4 waves), tile 128x128, BK=64.
// LDS: 128 rows x 128B; 16B chunk c of row r stored at chunk c^(r&7).
// -------------------------------------------------------------------------
template<int MODE, bool A_BF16, bool B_BF16>
__global__ __launch_bounds__(256, 2)
void gemm_bt(const void* __restrict__ Xv, const void* __restrict__ Wv,
             const float* __restrict__ bias, void* __restrict__ outv,
             const int* __restrict__ pos) {
  __shared__ bf16 sA[128*64];
  __shared__ bf16 sB[128*64];

  const float* Xf = (const float*)Xv;
  const bf16*  Xb = (const bf16*) Xv;
  const float* Wf = (const float*)Wv;
  const bf16*  Wb = (const bf16*) Wv;

  const int tid  = threadIdx.x;
  const int lane = tid & 63, wid = tid >> 6;
  const int q4 = lane >> 4, l15 = lane & 15;
  const int rb = blockIdx.x * 128;
  const int cb = blockIdx.y * 128;
  const int wm = (wid >> 1) * 64, wn = (wid & 1) * 64;

  f32x4 acc[4][4];
  const f32x4 z4 = {0.f, 0.f, 0.f, 0.f};
#pragma unroll
  for (int i = 0; i < 4; ++i)
#pragma unroll
    for (int j = 0; j < 4; ++j) acc[i][j] = z4;

  for (int kt = 0; kt < 16; ++kt) {
    const int k0 = kt * 64;
    // async bf16 staging first (no VGPR round trip)
    if (A_BF16) {
#pragma unroll
      for (int i = 0; i < 4; ++i) {
        int o  = i*4096 + tid*16;
        int rr = o >> 7;
        int c0 = ((o >> 4) & 7) ^ (rr & 7);
        gload16((char*)sA + i*4096 + (wid << 10),
                Xb + (size_t)(rb + rr)*D_MODEL + k0 + c0*8);
      }
    }
    if (B_BF16) {
#pragma unroll
      for (int i = 0; i < 4; ++i) {
        int o  = i*4096 + tid*16;
        int rr = o >> 7;
        int c0 = ((o >> 4) & 7) ^ (rr & 7);
        gload16((char*)sB + i*4096 + (wid << 10),
                Wb + (size_t)(cb + rr)*D_MODEL + k0 + c0*8);
      }
    }
    if (!A_BF16) {
#pragma unroll
      for (int i = 0; i < 4; ++i) {
        int e  = i*2048 + tid*8;
        int rr = e >> 6, c = (e >> 3) & 7, cs = c ^ (rr & 7);
        const float* s0 = Xf + (size_t)(rb + rr)*D_MODEL + k0 + c*8;
        *(bf16x8*)((char*)sA + rr*128 + cs*16) =
            cvt8rne(*(const float4*)s0, *(const float4*)(s0 + 4));
      }
    }
    if (!B_BF16) {
#pragma unroll
      for (int i = 0; i < 4; ++i) {
        int e  = i*2048 + tid*8;
        int rr = e >> 6, c = (e >> 3) & 7, cs = c ^ (rr & 7);
        const float* s1 = Wf + (size_t)(cb + rr)*D_MODEL + k0 + c*8;
        *(bf16x8*)((char*)sB + rr*128 + cs*16) =
            cvt8rne(*(const float4*)s1, *(const float4*)(s1 + 4));
      }
    }
    __syncthreads();
#pragma unroll
    for (int kq = 0; kq < 2; ++kq) {
      bf16x8 af[4], bfr[4];
      const int cc = (kq*4 + q4) ^ (l15 & 7);
#pragma unroll
      for (int mi = 0; mi < 4; ++mi) {
        int r = wm + mi*16 + l15;
        af[mi] = *(const bf16x8*)((const char*)sA + r*128 + cc*16);
      }
#pragma unroll
      for (int ni = 0; ni < 4; ++ni) {
        int r = wn + ni*16 + l15;
        bfr[ni] = *(const bf16x8*)((const char*)sB + r*128 + cc*16);
      }
#pragma unroll
      for (int mi = 0; mi < 4; ++mi)
#pragma unroll
        for (int ni = 0; ni < 4; ++ni)
          acc[mi][ni] = MFMA(af[mi], bfr[ni], acc[mi][ni]);
    }
    __syncthreads();
  }

  // ---------------- epilogue ----------------
  if (MODE == 0) {
    float* outF = (float*)outv;
#pragma unroll
    for (int ni = 0; ni < 4; ++ni) {
      int col = cb + wn + ni*16 + l15;
      float bv = bias[col];
#pragma unroll
      for (int mi = 0; mi < 4; ++mi) {
        int row0 = rb + wm + mi*16 + q4*4;
#pragma unroll
        for (int r = 0; r < 4; ++r)
          outF[(size_t)(row0 + r)*D_MODEL + col] = acc[mi][ni][r] + bv;
      }
    }
  } else if (MODE == 1) {
    bf16* out = (bf16*)outv;
#pragma unroll
    for (int ni = 0; ni < 4; ++ni) {
      int col = cb + wn + ni*16 + l15;
      int h = col >> 6, d = col & 63;
      float bv = bias[col];
#pragma unroll
      for (int mi = 0; mi < 4; ++mi) {
#pragma unroll
        for (int r = 0; r < 4; ++r) {
          int row = rb + wm + mi*16 + q4*4 + r;
          int b = row >> 11, m = row & 2047;
          out[(size_t)((b*N_HEADS + h)*SEQ + m)*HEAD_D + d] =
              __float2bfloat16(acc[mi][ni][r] + bv);
        }
      }
    }
  } else if (MODE == 2) {  // flipped: row = h*64+d, col = b*2048+m
    bf16* out = (bf16*)outv;
#pragma unroll
    for (int mi = 0; mi < 4; ++mi) {
#pragma unroll
      for (int r = 0; r < 4; ++r) {
        int row = rb + wm + mi*16 + q4*4 + r;
        float bv = bias[row];
#pragma unroll
        for (int ni = 0; ni < 4; ++ni) {
          int col = cb + wn + ni*16 + l15;
          int b = col >> 11, m = col & 2047;
          out[(size_t)(b*D_MODEL + row)*SEQ + m] =
              __float2bfloat16(acc[mi][ni][r] + bv);
        }
      }
    }
  } else { // MODE 3: Q with RoPE, scaled by SCALE_Q
    bf16* out = (bf16*)outv;
    // positions sorted ascending ending ~4090 => int32 slot NROWS-1 is 0 only
    // when storage is int64 (hi half of last element).
    const bool is64 = (pos[NROWS - 1] == 0);
    const float CLOG = 13.287712379549449f / 32.0f;  // log2(10000)/32
    float invf0 = exp2f(-(float)(l15)      * CLOG);
    float invf1 = exp2f(-(float)(l15 + 16) * CLOG);
    int h = (cb + wn) >> 6;  // wave covers exactly one head (64 cols)
#pragma unroll
    for (int ni = 0; ni < 2; ++ni) {
      int col1 = cb + wn + ni*16 + l15;
      int d = ni*16 + l15;          // d in [0,32)
      float invf = (ni == 0) ? invf0 : invf1;
      float b1 = bias[col1];
      float b2 = bias[col1 + 32];
#pragma unroll
      for (int mi = 0; mi < 4; ++mi) {
#pragma unroll
        for (int r = 0; r < 4; ++r) {
          int row = rb + wm + mi*16 + q4*4 + r;
          int b = row >> 11, t = row & 2047;
          int pv = is64 ? pos[2*row] : pos[row];
          float ang = (float)pv * invf;
          float sn, cs;
          __sincosf(ang, &sn, &cs);
          float q1 = acc[mi][ni][r]   + b1;
          float q2 = acc[mi][ni+2][r] + b2;
          size_t base = (size_t)((b*N_HEADS + h)*SEQ + t)*HEAD_D;
          out[base + d]      = __float2bfloat16((q1*cs - q2*sn) * SCALE_Q);
          out[base + d + 32] = __float2bfloat16((q2*cs + q1*sn) * SCALE_Q);
        }
      }
    }
  }
}

// -------------------------------------------------------------------------
// Flash attention. grid = (T/128, B*H). block = 256 (4 waves x 32 q-rows).
// Q[bh][t][d] (pre-scaled by SCALE_Q), K[bh][m][d], VT[bh][d][m] bf16.
// O -> [b][t][h*64+d]. Softmax in base 2 (scale folded into Q).
// -------------------------------------------------------------------------
__global__ __launch_bounds__(256, 2)
void attn_kernel(const bf16* __restrict__ Q, const bf16* __restrict__ K,
                 const bf16* __restrict__ VT, bf16* __restrict__ O) {
  // sP (128x136 bf16 = 34816B) aliases sK (128x64 = 16KB); sVT separate.
  __shared__ __align__(16) char smem[34816 + 16384];
  bf16* sP  = (bf16*)smem;
  bf16* sK  = (bf16*)smem;
  bf16* sVT = (bf16*)(smem + 34816);

  const int tid  = threadIdx.x;
  const int lane = tid & 63, wid = tid >> 6;
  const int q4 = lane >> 4, l15 = lane & 15;
  const int bh = blockIdx.y;
  const int qb = blockIdx.x * 128;

  const bf16* Qp  = Q  + (size_t)bh * SEQ * HEAD_D;
  const bf16* Kp  = K  + (size_t)bh * SEQ * HEAD_D;
  const bf16* VTp = VT + (size_t)bh * HEAD_D * SEQ;

  // resident Q fragments: wave owns rows [qb+wid*32, +32)
  bf16x8 qf[2][2];
#pragma unroll
  for (int mi = 0; mi < 2; ++mi)
#pragma unroll
    for (int kq = 0; kq < 2; ++kq) {
      int t = qb + wid*32 + mi*16 + l15;
      qf[mi][kq] = *(const bf16x8*)(Qp + (size_t)t*HEAD_D + kq*32 + q4*8);
    }

  const f32x4 z4 = {0.f, 0.f, 0.f, 0.f};
  f32x4 oacc[2][4];
  float mrow[2][4], lrow[2][4];   // lrow is a PER-LANE partial sum
#pragma unroll
  for (int mi = 0; mi < 2; ++mi) {
#pragma unroll
    for (int nd = 0; nd < 4; ++nd) oacc[mi][nd] = z4;
#pragma unroll
    for (int r = 0; r < 4; ++r) { mrow[mi][r] = -3.0e38f; lrow[mi][r] = 0.f; }
  }

  for (int kv = 0; kv < 16; ++kv) {
    const int m0 = kv * 128;
    // stage K tile (128x64, swizzled 16B chunks within 128B rows)
#pragma unroll
    for (int i = 0; i < 4; ++i) {
      int o  = i*4096 + tid*16;
      int rr = o >> 7;
      int c0 = ((o >> 4) & 7) ^ (rr & 7);
      gload16((char*)sK + i*4096 + (wid << 10),
              Kp + (size_t)(m0 + rr)*HEAD_D + c0*8);
    }
    // stage VT tile (64x128, swizzled 16B chunks within 256B rows)
#pragma unroll
    for (int i = 0; i < 4; ++i) {
      int o  = i*4096 + tid*16;
      int rr = o >> 8;
      int c0 = ((o >> 4) & 15) ^ (rr & 7);
      gload16((char*)sVT + i*4096 + (wid << 10),
              VTp + (size_t)rr*SEQ + m0 + c0*8);
    }
    __syncthreads();

    // S = Q K^T (already includes softmax scale in base-2)
    f32x4 s[2][8];
#pragma unroll
    for (int mi = 0; mi < 2; ++mi)
#pragma unroll
      for (int ni = 0; ni < 8; ++ni) s[mi][ni] = z4;
#pragma unroll
    for (int kq = 0; kq < 2; ++kq) {
      const int cc = (kq*4 + q4) ^ (l15 & 7);
#pragma unroll
      for (int ni = 0; ni < 8; ++ni) {
        int m = ni*16 + l15;
        bf16x8 bk = *(const bf16x8*)((const char*)sK + m*128 + cc*16);
        s[0][ni] = MFMA(qf[0][kq], bk, s[0][ni]);
        s[1][ni] = MFMA(qf[1][kq], bk, s[1][ni]);
      }
    }
    __syncthreads();   // all sK reads done before sP (aliased) is written

    // online softmax; l kept as per-lane partial (alpha is row-uniform)
#pragma unroll
    for (int mi = 0; mi < 2; ++mi) {
      float mloc[4] = {-3.0e38f, -3.0e38f, -3.0e38f, -3.0e38f};
#pragma unroll
      for (int ni = 0; ni < 8; ++ni)
#pragma unroll
        for (int r = 0; r < 4; ++r) mloc[r] = fmaxf(mloc[r], s[mi][ni][r]);
#pragma unroll
      for (int off = 1; off < 16; off <<= 1)
#pragma unroll
        for (int r = 0; r < 4; ++r)
          mloc[r] = fmaxf(mloc[r], __shfl_xor(mloc[r], off, 64));
      float al[4], rs[4] = {0.f, 0.f, 0.f, 0.f};
#pragma unroll
      for (int r = 0; r < 4; ++r) {
        float mn = fmaxf(mrow[mi][r], mloc[r]);
        al[r] = EXP2(mrow[mi][r] - mn);
        mrow[mi][r] = mn;
      }
#pragma unroll
      for (int ni = 0; ni < 8; ++ni)
#pragma unroll
        for (int r = 0; r < 4; ++r) {
          float p = EXP2(s[mi][ni][r] - mrow[mi][r]);
          s[mi][ni][r] = p;
          rs[r] += p;
        }
#pragma unroll
      for (int r = 0; r < 4; ++r) lrow[mi][r] = lrow[mi][r]*al[r] + rs[r];
#pragma unroll
      for (int nd = 0; nd < 4; ++nd)
#pragma unroll
        for (int r = 0; r < 4; ++r) oacc[mi][nd][r] *= al[r];
      // P: C-layout scatter into padded LDS (ld = 136 elems)
#pragma unroll
      for (int ni = 0; ni < 8; ++ni)
#pragma unroll
        for (int r = 0; r < 4; ++r)
          sP[(wid*32 + mi*16 + q4*4 + r)*136 + ni*16 + l15] =
              __float2bfloat16(s[mi][ni][r]);
    }
    __syncthreads();

    // O += P @ V   (A from sP rows, B from sVT rows = V^T)
#pragma unroll
    for (int kk = 0; kk < 4; ++kk) {
      bf16x8 bv[4];
      const int cc = (kk*4 + q4) ^ (l15 & 7);
#pragma unroll
      for (int nd = 0; nd < 4; ++nd) {
        int d = nd*16 + l15;
        bv[nd] = *(const bf16x8*)((const char*)sVT + d*256 + cc*16);
      }
#pragma unroll
      for (int mi = 0; mi < 2; ++mi) {
        bf16x8 ap = *(const bf16x8*)((const char*)sP +
                     (wid*32 + mi*16 + l15)*272 + kk*64 + q4*16);
#pragma unroll
        for (int nd = 0; nd < 4; ++nd)
          oacc[mi][nd] = MFMA(ap, bv[nd], oacc[mi][nd]);
      }
    }
    __syncthreads();   // PV reads done before next tile overwrites sK/sVT
  }

  // epilogue: reduce per-lane l partials once, O /= l, write [b][t][h*64+d]
  const int b = bh >> 4, h = bh & 15;
#pragma unroll
  for (int mi = 0; mi < 2; ++mi) {
#pragma unroll
    for (int r = 0; r < 4; ++r) {
      float l = lrow[mi][r];
      l += __shfl_xor(l, 1, 64);
      l += __shfl_xor(l, 2, 64);
      l += __shfl_xor(l, 4, 64);
      l += __shfl_xor(l, 8, 64);
      float inv = 1.0f / l;
      int t = qb + wid*32 + mi*16 + q4*4 + r;
#pragma unroll
      for (int nd = 0; nd < 4; ++nd) {
        int d = nd*16 + l15;
        O[(size_t)(b*SEQ + t)*D_MODEL + h*HEAD_D + d] =
            __float2bfloat16(oacc[mi][nd][r] * inv);
      }
    }
  }
}

// -------------------------------------------------------------------------
extern "C" void kernel_launch(void* const* d_in, const int* in_sizes, int n_in,
                              void* d_out, int out_size, void* d_ws, size_t ws_size,
                              hipStream_t stream) {
  const void* query = d_in[0];             // f32 [B,T,D]
  const void* key   = d_in[1];             // f32 [B,M,D]
  const void* value = d_in[2];             // f32 [B,M,D]
  const int*  pos   = (const int*)d_in[3];
  const float* Wq = (const float*)d_in[4];  const float* bq = (const float*)d_in[5];
  const float* Wk = (const float*)d_in[6];  const float* bk = (const float*)d_in[7];
  const float* Wv = (const float*)d_in[8];  const float* bv = (const float*)d_in[9];
  const float* Wo = (const float*)d_in[10]; const float* bo = (const float*)d_in[11];

  // ws layout (64 MB total, same footprint as the passing round-2 config):
  // [0,16M)  qbuf  bf16 [b,h,t,d]
  // [16,32M) kbuf  bf16 [b,h,m,d]
  // [32,48M) vtbuf bf16 [b,h,d,m]
  // [48,64M) obuf  bf16 [b,t,h*64+d]; BEFORE attn its first 6MB holds the
  //          pre-converted bf16 weights (wq,wk,wv) — dead once attn writes it.
  char* ws = (char*)d_ws;
  bf16* qbuf  = (bf16*)(ws);
  bf16* kbuf  = (bf16*)(ws + (size_t)16777216);
  bf16* vtbuf = (bf16*)(ws + (size_t)33554432);
  bf16* obuf  = (bf16*)(ws + (size_t)50331648);
  bf16* wqb = obuf;                       // 1M bf16 = 2MB
  bf16* wkb = obuf + (size_t)1048576;
  bf16* wvb = obuf + (size_t)2097152;

  dim3 blk(256);
  dim3 gproj(NROWS/128, D_MODEL/128);     // 64 x 8
  dim3 gprojT(D_MODEL/128, NROWS/128);    // 8 x 64 (flipped V)

  convw<<<512, blk, 0, stream>>>(Wq, wqb);
  convw<<<512, blk, 0, stream>>>(Wk, wkb);
  convw<<<512, blk, 0, stream>>>(Wv, wvb);

  // Q: A=query f32 (fused cvt), B=wq bf16 (async LDS), RoPE+scale epilogue
  gemm_bt<3, false, true ><<<gproj,  blk, 0, stream>>>(query, wqb, bq, qbuf, pos);
  // K: A=key f32, B=wk bf16
  gemm_bt<1, false, true ><<<gproj,  blk, 0, stream>>>(key,   wkb, bk, kbuf, nullptr);
  // V^T: flipped — A=wv bf16, B=value f32; C' = Wv X^T lands in [d][m]
  gemm_bt<2, true,  false><<<gprojT, blk, 0, stream>>>(wvb, value, bv, vtbuf, nullptr);

  attn_kernel<<<dim3(SEQ/128, BATCH*N_HEADS), blk, 0, stream>>>(qbuf, kbuf, vtbuf, obuf);

  // O: A=obuf bf16 (async LDS), B=Wo f32 (fused cvt), f32 out
  gemm_bt<0, true,  false><<<gproj,  blk, 0, stream>>>(obuf, Wo, bo, d_out, nullptr);
  (void)in_sizes; (void)n_in; (void)out_size; (void)ws_size;
}